// Round 1
// baseline (322.636 us; speedup 1.0000x reference)
//
#include <hip/hip_runtime.h>
#include <hip/hip_bf16.h>
#include <cstdint>

#define BB 16384
#define HH 896
#define SS 448
#define QQ 256

typedef __attribute__((ext_vector_type(4))) float f32x4;
typedef __attribute__((ext_vector_type(8))) short bf16x8;

__device__ __forceinline__ short f2bf(float f){
  union { float f; uint32_t u; } x; x.f = f;
  uint32_t r = (x.u + 0x7fffu + ((x.u >> 16) & 1u)) >> 16;
  return (short)r;
}
__device__ __forceinline__ float bf2f(short b){
  union { uint32_t u; float f; } x; x.u = ((uint32_t)(uint16_t)b) << 16;
  return x.f;
}

// ---------------- cast kernels ----------------
__global__ void cast4_kernel(const float* __restrict__ src, short* __restrict__ dst, long n4){
  long i = (long)blockIdx.x * blockDim.x + threadIdx.x;
  if (i >= n4) return;
  const float4 v = reinterpret_cast<const float4*>(src)[i];
  short4 o; o.x = f2bf(v.x); o.y = f2bf(v.y); o.z = f2bf(v.z); o.w = f2bf(v.w);
  reinterpret_cast<short4*>(dst)[i] = o;
}

__global__ void castpad_kernel(const float* __restrict__ src, short* __restrict__ dst,
                               int srows, int scols, int dcols, int total){
  int i = blockIdx.x * blockDim.x + threadIdx.x;
  if (i >= total) return;
  int r = i / dcols, c = i - r * dcols;
  float v = (r < srows && c < scols) ? src[(long)r * scols + c] : 0.f;
  dst[i] = f2bf(v);
}

// ---------------- GEMM: C = A @ Bt^T ----------------
// A: [M,K] bf16 row-major (lda), Bt: [N,K] bf16 row-major (ldb)
// BM=BN=128, BK=64, 256 threads = 4 waves (2x2), wave tile 64x64 = 4x4 mfma frags
#define EP_BF16 0
#define EP_RELU_BIAS_BF16 1
#define EP_BIAS_F32 2

template<int EP>
__global__ __launch_bounds__(256)
void gemm_bt(const short* __restrict__ A, int lda,
             const short* __restrict__ Bt, int ldb,
             void* __restrict__ Cv, int ldc,
             const float* __restrict__ bias, int nbias,
             int K)
{
  __shared__ short As[128 * 64];
  __shared__ short Bs[128 * 64];
  const int tid = threadIdx.x;
  const int wv = tid >> 6, ln = tid & 63;
  const int wr = wv >> 1, wc = wv & 1;
  const long m0 = (long)blockIdx.y * 128;
  const long n0 = (long)blockIdx.x * 128;

  f32x4 acc[4][4] = {};

  const int lr = ln & 15;
  const int lkbase = (ln >> 4) * 8;

  // staging geometry: chunk = wv*4+i (0..15); lane l covers 8 bf16 at elem chunk*512+l*8
  const int e0 = ln * 8;
  for (int k0 = 0; k0 < K; k0 += 64) {
    __syncthreads();
#pragma unroll
    for (int i = 0; i < 4; i++) {
      int chunk = wv * 4 + i;
      int e = chunk * 512 + e0;
      int row = e >> 6, col = e & 63;
      const short* g = A + (m0 + row) * lda + k0 + col;
      __builtin_amdgcn_global_load_lds((const __attribute__((address_space(1))) void*)g,
                                       (__attribute__((address_space(3))) void*)&As[chunk * 512],
                                       16, 0, 0);
    }
#pragma unroll
    for (int i = 0; i < 4; i++) {
      int chunk = wv * 4 + i;
      int e = chunk * 512 + e0;
      int row = e >> 6, col = e & 63;
      const short* g = Bt + (n0 + row) * ldb + k0 + col;
      __builtin_amdgcn_global_load_lds((const __attribute__((address_space(1))) void*)g,
                                       (__attribute__((address_space(3))) void*)&Bs[chunk * 512],
                                       16, 0, 0);
    }
    __syncthreads();
#pragma unroll
    for (int ks = 0; ks < 2; ks++) {
      bf16x8 a[4], b[4];
#pragma unroll
      for (int m = 0; m < 4; m++)
        a[m] = *reinterpret_cast<const bf16x8*>(&As[(wr * 64 + m * 16 + lr) * 64 + ks * 32 + lkbase]);
#pragma unroll
      for (int n = 0; n < 4; n++)
        b[n] = *reinterpret_cast<const bf16x8*>(&Bs[(wc * 64 + n * 16 + lr) * 64 + ks * 32 + lkbase]);
#pragma unroll
      for (int m = 0; m < 4; m++)
#pragma unroll
        for (int n = 0; n < 4; n++)
          acc[m][n] = __builtin_amdgcn_mfma_f32_16x16x32_bf16(a[m], b[n], acc[m][n], 0, 0, 0);
    }
  }

  // epilogue: C/D layout col=lane&15, row=(lane>>4)*4+reg
  const int lc = ln & 15;
  const int r4 = (ln >> 4) * 4;
#pragma unroll
  for (int m = 0; m < 4; m++) {
#pragma unroll
    for (int n = 0; n < 4; n++) {
      long col = n0 + wc * 64 + n * 16 + lc;
#pragma unroll
      for (int reg = 0; reg < 4; reg++) {
        long row = m0 + wr * 64 + m * 16 + r4 + reg;
        float v = acc[m][n][reg];
        if (EP == EP_BF16) {
          ((short*)Cv)[row * ldc + col] = f2bf(v);
        } else if (EP == EP_RELU_BIAS_BF16) {
          float bv = (col < nbias) ? bias[col] : 0.f;
          v += bv;
          v = v > 0.f ? v : 0.f;
          ((short*)Cv)[row * ldc + col] = f2bf(v);
        } else {
          v += bias[col];
          ((float*)Cv)[row * ldc + col] = v;
        }
      }
    }
  }
}

// ---------------- gates (elementwise + tiny input projections) ----------------
__global__ void gates_kernel(const float* __restrict__ prev_y,
                             const float* __restrict__ prev_hidden,
                             const float* __restrict__ ccoarse,
                             const float* __restrict__ Icw,   // [3S,2]
                             const float* __restrict__ Ifw,   // [3S,3]
                             const float* __restrict__ bu,
                             const float* __restrict__ br,
                             const float* __restrict__ be,
                             const short* __restrict__ Rh,    // [B,3H] bf16
                             float* __restrict__ hid_out,     // [B,H] f32 (d_out slot)
                             short* __restrict__ hid_bf)      // [B,H] bf16 (ws)
{
  const int b = blockIdx.y;
  const int h = blockIdx.x * 128 + threadIdx.x;
  const float py0 = prev_y[2 * b], py1 = prev_y[2 * b + 1], c0 = ccoarse[b];
  float iu, ir, ie;
  if (h < SS) {
    int j = h;
    iu = py0 * Icw[2 * j]            + py1 * Icw[2 * j + 1];
    ir = py0 * Icw[2 * (SS + j)]     + py1 * Icw[2 * (SS + j) + 1];
    ie = py0 * Icw[2 * (2 * SS + j)] + py1 * Icw[2 * (2 * SS + j) + 1];
  } else {
    int j = h - SS;
    iu = py0 * Ifw[3 * j]            + py1 * Ifw[3 * j + 1]            + c0 * Ifw[3 * j + 2];
    ir = py0 * Ifw[3 * (SS + j)]     + py1 * Ifw[3 * (SS + j) + 1]     + c0 * Ifw[3 * (SS + j) + 2];
    ie = py0 * Ifw[3 * (2 * SS + j)] + py1 * Ifw[3 * (2 * SS + j) + 1] + c0 * Ifw[3 * (2 * SS + j) + 2];
  }
  const long base = (long)b * (3 * HH);
  float ru = bf2f(Rh[base + h]);
  float rr = bf2f(Rh[base + HH + h]);
  float re = bf2f(Rh[base + 2 * HH + h]);
  float u = 1.f / (1.f + __expf(-(ru + iu + bu[h])));
  float r = 1.f / (1.f + __expf(-(rr + ir + br[h])));
  float e = tanhf(r * re + ie + be[h]);
  float ph = prev_hidden[(long)b * HH + h];
  float hd = u * ph + (1.f - u) * e;
  hid_out[(long)b * HH + h] = hd;
  hid_bf[(long)b * HH + h] = f2bf(hd);
}

// ---------------- launch ----------------
extern "C" void kernel_launch(void* const* d_in, const int* in_sizes, int n_in,
                              void* d_out, int out_size, void* d_ws, size_t ws_size,
                              hipStream_t stream)
{
  (void)in_sizes; (void)n_in; (void)out_size; (void)ws_size;
  const float* prev_y      = (const float*)d_in[0];
  const float* prev_hidden = (const float*)d_in[1];
  const float* ccoarse     = (const float*)d_in[2];
  const float* R_w  = (const float*)d_in[3];
  const float* Ic_w = (const float*)d_in[4];
  const float* If_w = (const float*)d_in[5];
  const float* bu   = (const float*)d_in[6];
  const float* br   = (const float*)d_in[7];
  const float* be   = (const float*)d_in[8];
  const float* O1w  = (const float*)d_in[9];
  const float* O1b  = (const float*)d_in[10];
  const float* O2w  = (const float*)d_in[11];
  const float* O2b  = (const float*)d_in[12];
  const float* O3w  = (const float*)d_in[13];
  const float* O3b  = (const float*)d_in[14];
  const float* O4w  = (const float*)d_in[15];
  const float* O4b  = (const float*)d_in[16];

  float* out_coarse = (float*)d_out;
  float* out_fine   = out_coarse + (long)BB * QQ;
  float* hidden     = out_fine + (long)BB * QQ;

  char* ws = (char*)d_ws;
  short* Ah   = (short*)(ws + 0);          // B*H bf16           = 29,360,128 B
  short* Rwh  = (short*)(ws + 29360128);   // 3H*H bf16          =  4,816,896 B
  short* Rh   = (short*)(ws + 34177024);   // B*3H bf16          = 88,080,384 B
  short* hidb = (short*)(ws + 122257408);  // B*H bf16           = 29,360,128 B
  short* O1wb = (short*)(ws + 151617536);  // 512*448 bf16
  short* O3wb = (short*)(ws + 152076288);
  short* O2wb = (short*)(ws + 152535040);  // 256*512 bf16
  short* O4wb = (short*)(ws + 152797184);  // end: 153,059,328 B
  // t1/t2 alias the Ah+Rwh region (dead after the R-GEMM)
  short* t1   = (short*)(ws + 0);          // B*512 bf16 = 16,777,216 B
  short* t2   = (short*)(ws + 16777216);   // ends 33,554,432 < 34,177,024 OK

  // casts
  long nAh4 = (long)BB * HH / 4;   // 3,670,016
  cast4_kernel<<<(int)((nAh4 + 255) / 256), 256, 0, stream>>>(prev_hidden, Ah, nAh4);
  long nRw4 = (long)3 * HH * HH / 4; // 602,112
  cast4_kernel<<<(int)((nRw4 + 255) / 256), 256, 0, stream>>>(R_w, Rwh, nRw4);
  castpad_kernel<<<(512 * 448 + 255) / 256, 256, 0, stream>>>(O1w, O1wb, 448, 448, 448, 512 * 448);
  castpad_kernel<<<(512 * 448 + 255) / 256, 256, 0, stream>>>(O3w, O3wb, 448, 448, 448, 512 * 448);
  castpad_kernel<<<(256 * 512 + 255) / 256, 256, 0, stream>>>(O2w, O2wb, 256, 448, 512, 256 * 512);
  castpad_kernel<<<(256 * 512 + 255) / 256, 256, 0, stream>>>(O4w, O4wb, 256, 448, 512, 256 * 512);

  // R GEMM: M=B, N=3H=2688, K=H=896 -> Rh (bf16)
  gemm_bt<EP_BF16><<<dim3(2688 / 128, BB / 128), 256, 0, stream>>>(
      Ah, HH, Rwh, HH, Rh, 3 * HH, nullptr, 0, HH);

  // gates -> hidden (f32 to d_out) + hidb (bf16)
  gates_kernel<<<dim3(7, BB), 128, 0, stream>>>(prev_y, prev_hidden, ccoarse,
                                                Ic_w, If_w, bu, br, be, Rh, hidden, hidb);

  // heads: t = relu(h_half @ O^T + b)  (N padded to 512)
  gemm_bt<EP_RELU_BIAS_BF16><<<dim3(512 / 128, BB / 128), 256, 0, stream>>>(
      hidb, HH, O1wb, 448, t1, 512, O1b, 448, 448);
  gemm_bt<EP_RELU_BIAS_BF16><<<dim3(512 / 128, BB / 128), 256, 0, stream>>>(
      hidb + 448, HH, O3wb, 448, t2, 512, O3b, 448, 448);

  // out = t @ O^T + b  (K=512, padded cols are zero on both sides)
  gemm_bt<EP_BIAS_F32><<<dim3(256 / 128, BB / 128), 256, 0, stream>>>(
      t1, 512, O2wb, 512, out_coarse, 256, O2b, 256, 512);
  gemm_bt<EP_BIAS_F32><<<dim3(256 / 128, BB / 128), 256, 0, stream>>>(
      t2, 512, O4wb, 512, out_fine, 256, O4b, 256, 512);
}

// Round 2
// 268.190 us; speedup vs baseline: 1.2030x; 1.2030x over previous
//
#include <hip/hip_runtime.h>
#include <hip/hip_bf16.h>
#include <cstdint>

#define BB 16384
#define HH 896
#define SS 448
#define QQ 256
#define NPAD 2816   // 3H=2688 padded to 11*256

typedef __attribute__((ext_vector_type(4))) float f32x4;
typedef __attribute__((ext_vector_type(8))) short bf16x8;

__device__ __forceinline__ short f2bf(float f){
  union { float f; uint32_t u; } x; x.f = f;
  uint32_t r = (x.u + 0x7fffu + ((x.u >> 16) & 1u)) >> 16;
  return (short)r;
}
__device__ __forceinline__ float bf2f(short b){
  union { uint32_t u; float f; } x; x.u = ((uint32_t)(uint16_t)b) << 16;
  return x.f;
}

// ---------------- cast kernels ----------------
__global__ void cast4_kernel(const float* __restrict__ src, short* __restrict__ dst, long n4){
  long i = (long)blockIdx.x * blockDim.x + threadIdx.x;
  if (i >= n4) return;
  const float4 v = reinterpret_cast<const float4*>(src)[i];
  short4 o; o.x = f2bf(v.x); o.y = f2bf(v.y); o.z = f2bf(v.z); o.w = f2bf(v.w);
  reinterpret_cast<short4*>(dst)[i] = o;
}

__global__ void castpad_kernel(const float* __restrict__ src, short* __restrict__ dst,
                               int srows, int scols, int dcols, int total){
  int i = blockIdx.x * blockDim.x + threadIdx.x;
  if (i >= total) return;
  int r = i / dcols, c = i - r * dcols;
  float v = (r < srows && c < scols) ? src[(long)r * scols + c] : 0.f;
  dst[i] = f2bf(v);
}

// ================= 256x256 8-phase GEMM (R projection) =================
// C[M,N] = A[M,K] @ Bt[N,K]^T, all bf16, M%256==0, N (padded operand) %256==0,
// K%64==0. 512 threads = 8 waves (2M x 4N). Per-wave out 128x64.
// Wave wr: m-frag m -> tile rows m*32 + wr*16 (interleaved so quadrants 0,1
// touch only A-half0 rows [0,128), quadrants 2,3 only A-half1).
// LDS 128 KiB: A[2][256][64] + B[2][256][64], granule-XOR swizzled
// (16B granule gc at row r holds source granule gc^(r&7)); staging realizes
// the swizzle by pre-swizzling the per-lane GLOBAL address (linear LDS dest).
__global__ __launch_bounds__(512, 2)
void gemm256_bt(const short* __restrict__ A, int lda,
                const short* __restrict__ Bt, int ldb,
                short* __restrict__ C, int ldc, int Nvalid,
                int K, int nbn)
{
  __shared__ short smem[65536];   // 128 KiB
  const int tid = threadIdx.x;
  const int w  = tid >> 6, ln = tid & 63;
  const int wr = w >> 2,  wc = w & 3;
  const int lr = ln & 15;
  const int lg = ln >> 4;          // k-group 0..3
  const int srow = ln >> 3;        // staging: row within 8-row wave slice
  const int sgc  = (ln & 7) ^ srow; // staging: pre-swizzled source granule

  // bijective XCD swizzle (gridDim.x % 8 == 0)
  int wg = blockIdx.x;
  const int cpx = gridDim.x >> 3;
  wg = (wg & 7) * cpx + (wg >> 3);
  const int bm = wg / nbn, bn = wg - bm * nbn;
  const long m0 = (long)bm * 256, n0 = (long)bn * 256;

  f32x4 acc[8][4] = {};

  // stage one 128x64 half-tile (2 x global_load_lds dwordx4 per wave-slice)
  auto stage = [&](const short* __restrict__ src, int ld, long rbase, int k0,
                   int lbase /*elem*/, int h) {
#pragma unroll
    for (int i = 0; i < 2; ++i) {
      const int rloc = h * 128 + i * 64 + w * 8;            // wave-uniform
      const short* g = src + (rbase + rloc + srow) * (long)ld + k0 + sgc * 8;
      __builtin_amdgcn_global_load_lds(
          (const __attribute__((address_space(1))) void*)g,
          (__attribute__((address_space(3))) void*)&smem[lbase + rloc * 64],
          16, 0, 0);
    }
  };
  auto rd = [&](int lbase, int r, int ks) -> bf16x8 {
    const int gc = ks * 4 + lg;
    return *reinterpret_cast<const bf16x8*>(&smem[lbase + r * 64 + ((gc ^ (r & 7)) << 3)]);
  };

  const int NT = K >> 6;
  // prologue: tile 0 -> buf 0, order B0,B1,A0,A1
  stage(Bt, ldb, n0, 0, 32768, 0);
  stage(Bt, ldb, n0, 0, 32768, 1);
  stage(A,  lda, m0, 0, 0,     0);
  stage(A,  lda, m0, 0, 0,     1);
  asm volatile("s_waitcnt vmcnt(2)" ::: "memory");   // B0,B1,A0 arrived
  __builtin_amdgcn_s_barrier();
  asm volatile("" ::: "memory");
  __builtin_amdgcn_sched_barrier(0);

  for (int j = 0; j < NT; ++j) {
    const int Ab = (j & 1) * 16384;
    const int Bb = 32768 + (j & 1) * 16384;
    const int An = ((j + 1) & 1) * 16384;
    const int Bn = 32768 + ((j + 1) & 1) * 16384;
    const bool pf = (j + 1 < NT);
    const int k1 = (j + 1) << 6;
    bf16x8 b[4][2];
#pragma unroll
    for (int q = 0; q < 4; ++q) {
      // ---- ds-load register subtiles ----
      bf16x8 a[2][2];
#pragma unroll
      for (int dm = 0; dm < 2; ++dm)
#pragma unroll
        for (int ks = 0; ks < 2; ++ks)
          a[dm][ks] = rd(Ab, q * 64 + dm * 32 + wr * 16 + lr, ks);
      if (q == 0) {
#pragma unroll
        for (int n = 0; n < 4; ++n)
#pragma unroll
          for (int ks = 0; ks < 2; ++ks)
            b[n][ks] = rd(Bb, wc * 64 + n * 16 + lr, ks);
      }
      // ---- stage 1 half-tile of next K-tile ----
      if (pf) {
        if      (q == 0) stage(Bt, ldb, n0, k1, Bn, 0);
        else if (q == 1) stage(Bt, ldb, n0, k1, Bn, 1);
        else if (q == 2) stage(A,  lda, m0, k1, An, 0);
        else             stage(A,  lda, m0, k1, An, 1);
      }
      asm volatile("" ::: "memory");
      __builtin_amdgcn_s_barrier();
      asm volatile("s_waitcnt lgkmcnt(0)" ::: "memory");
      __builtin_amdgcn_sched_barrier(0);
      // ---- MFMA cluster: one C-quadrant x K=64 (16 MFMA) ----
      __builtin_amdgcn_s_setprio(1);
#pragma unroll
      for (int dm = 0; dm < 2; ++dm)
#pragma unroll
        for (int n = 0; n < 4; ++n)
#pragma unroll
          for (int ks = 0; ks < 2; ++ks)
            acc[2 * q + dm][n] = __builtin_amdgcn_mfma_f32_16x16x32_bf16(
                a[dm][ks], b[n][ks], acc[2 * q + dm][n], 0, 0, 0);
      __builtin_amdgcn_s_setprio(0);
      __builtin_amdgcn_sched_barrier(0);
      // ---- counted vmcnt checkpoints (before the closing barrier) ----
      if (q == 1) {
        // guard A1(j) for phases 2,3; outstanding allowed: B0,B1 of j+1
        if (pf) asm volatile("s_waitcnt vmcnt(4)" ::: "memory");
        else    asm volatile("s_waitcnt vmcnt(0)" ::: "memory");
      } else if (q == 3) {
        // guard B0,B1,A0 of j+1 for next tile's phase 0; allow A1(j+1)
        asm volatile("s_waitcnt vmcnt(2)" ::: "memory");
      }
      asm volatile("" ::: "memory");
      __builtin_amdgcn_s_barrier();
      asm volatile("" ::: "memory");
      __builtin_amdgcn_sched_barrier(0);
    }
  }

  // epilogue: C/D layout col=lane&15, row=(lane>>4)*4+reg
  const int lc = ln & 15, rg = lg * 4;
#pragma unroll
  for (int n = 0; n < 4; ++n) {
    long col = n0 + wc * 64 + n * 16 + lc;
    if (col < Nvalid) {
#pragma unroll
      for (int m = 0; m < 8; ++m) {
        long row = m0 + m * 32 + wr * 16 + rg;
#pragma unroll
        for (int reg = 0; reg < 4; ++reg)
          C[(row + reg) * (long)ldc + col] = f2bf(acc[m][n][reg]);
      }
    }
  }
}

// ---------------- 128x128 GEMM (heads), z-paired ----------------
#define EP_RELU_BIAS_BF16 1
#define EP_BIAS_F32 2

template<int EP>
__global__ __launch_bounds__(256)
void gemm_bt(const short* __restrict__ A0, const short* __restrict__ A1, int lda,
             const short* __restrict__ W0, const short* __restrict__ W1, int ldb,
             void* __restrict__ C0v, void* __restrict__ C1v, int ldc,
             const float* __restrict__ bias0, const float* __restrict__ bias1, int nbias,
             int K)
{
  const short* A  = blockIdx.z ? A1 : A0;
  const short* Bt = blockIdx.z ? W1 : W0;
  void* Cv        = blockIdx.z ? C1v : C0v;
  const float* bias = blockIdx.z ? bias1 : bias0;

  __shared__ short As[128 * 64];
  __shared__ short Bs[128 * 64];
  const int tid = threadIdx.x;
  const int wv = tid >> 6, ln = tid & 63;
  const int wr = wv >> 1, wc = wv & 1;
  const long m0 = (long)blockIdx.y * 128;
  const long n0 = (long)blockIdx.x * 128;

  f32x4 acc[4][4] = {};
  const int lr = ln & 15;
  const int lkbase = (ln >> 4) * 8;
  const int e0 = ln * 8;
  for (int k0 = 0; k0 < K; k0 += 64) {
    __syncthreads();
#pragma unroll
    for (int i = 0; i < 4; i++) {
      int chunk = wv * 4 + i;
      int e = chunk * 512 + e0;
      int row = e >> 6, col = e & 63;
      const short* g = A + (m0 + row) * lda + k0 + col;
      __builtin_amdgcn_global_load_lds((const __attribute__((address_space(1))) void*)g,
                                       (__attribute__((address_space(3))) void*)&As[chunk * 512],
                                       16, 0, 0);
    }
#pragma unroll
    for (int i = 0; i < 4; i++) {
      int chunk = wv * 4 + i;
      int e = chunk * 512 + e0;
      int row = e >> 6, col = e & 63;
      const short* g = Bt + (n0 + row) * ldb + k0 + col;
      __builtin_amdgcn_global_load_lds((const __attribute__((address_space(1))) void*)g,
                                       (__attribute__((address_space(3))) void*)&Bs[chunk * 512],
                                       16, 0, 0);
    }
    __syncthreads();
#pragma unroll
    for (int ks = 0; ks < 2; ks++) {
      bf16x8 a[4], b[4];
#pragma unroll
      for (int m = 0; m < 4; m++)
        a[m] = *reinterpret_cast<const bf16x8*>(&As[(wr * 64 + m * 16 + lr) * 64 + ks * 32 + lkbase]);
#pragma unroll
      for (int n = 0; n < 4; n++)
        b[n] = *reinterpret_cast<const bf16x8*>(&Bs[(wc * 64 + n * 16 + lr) * 64 + ks * 32 + lkbase]);
#pragma unroll
      for (int m = 0; m < 4; m++)
#pragma unroll
        for (int n = 0; n < 4; n++)
          acc[m][n] = __builtin_amdgcn_mfma_f32_16x16x32_bf16(a[m], b[n], acc[m][n], 0, 0, 0);
    }
  }

  const int lc = ln & 15;
  const int r4 = (ln >> 4) * 4;
#pragma unroll
  for (int m = 0; m < 4; m++) {
#pragma unroll
    for (int n = 0; n < 4; n++) {
      long col = n0 + wc * 64 + n * 16 + lc;
#pragma unroll
      for (int reg = 0; reg < 4; reg++) {
        long row = m0 + wr * 64 + m * 16 + r4 + reg;
        float v = acc[m][n][reg];
        if (EP == EP_RELU_BIAS_BF16) {
          float bv = (col < nbias) ? bias[col] : 0.f;
          v += bv;
          v = v > 0.f ? v : 0.f;
          ((short*)Cv)[row * ldc + col] = f2bf(v);
        } else {
          v += bias[col];
          ((float*)Cv)[row * ldc + col] = v;
        }
      }
    }
  }
}

// ---------------- gates ----------------
__global__ void gates_kernel(const float* __restrict__ prev_y,
                             const float* __restrict__ prev_hidden,
                             const float* __restrict__ ccoarse,
                             const float* __restrict__ Icw,
                             const float* __restrict__ Ifw,
                             const float* __restrict__ bu,
                             const float* __restrict__ br,
                             const float* __restrict__ be,
                             const short* __restrict__ Rh,    // [B,2688] bf16
                             float* __restrict__ hid_out,
                             short* __restrict__ hid_bf)
{
  const int b = blockIdx.y;
  const int h = blockIdx.x * 128 + threadIdx.x;
  const float py0 = prev_y[2 * b], py1 = prev_y[2 * b + 1], c0 = ccoarse[b];
  float iu, ir, ie;
  if (h < SS) {
    int j = h;
    iu = py0 * Icw[2 * j]            + py1 * Icw[2 * j + 1];
    ir = py0 * Icw[2 * (SS + j)]     + py1 * Icw[2 * (SS + j) + 1];
    ie = py0 * Icw[2 * (2 * SS + j)] + py1 * Icw[2 * (2 * SS + j) + 1];
  } else {
    int j = h - SS;
    iu = py0 * Ifw[3 * j]            + py1 * Ifw[3 * j + 1]            + c0 * Ifw[3 * j + 2];
    ir = py0 * Ifw[3 * (SS + j)]     + py1 * Ifw[3 * (SS + j) + 1]     + c0 * Ifw[3 * (SS + j) + 2];
    ie = py0 * Ifw[3 * (2 * SS + j)] + py1 * Ifw[3 * (2 * SS + j) + 1] + c0 * Ifw[3 * (2 * SS + j) + 2];
  }
  const long base = (long)b * (3 * HH);
  float ru = bf2f(Rh[base + h]);
  float rr = bf2f(Rh[base + HH + h]);
  float re = bf2f(Rh[base + 2 * HH + h]);
  float u = 1.f / (1.f + __expf(-(ru + iu + bu[h])));
  float r = 1.f / (1.f + __expf(-(rr + ir + br[h])));
  float e = tanhf(r * re + ie + be[h]);
  float ph = prev_hidden[(long)b * HH + h];
  float hd = u * ph + (1.f - u) * e;
  hid_out[(long)b * HH + h] = hd;
  hid_bf[(long)b * HH + h] = f2bf(hd);
}

// ---------------- launch ----------------
extern "C" void kernel_launch(void* const* d_in, const int* in_sizes, int n_in,
                              void* d_out, int out_size, void* d_ws, size_t ws_size,
                              hipStream_t stream)
{
  (void)in_sizes; (void)n_in; (void)out_size; (void)ws_size;
  const float* prev_y      = (const float*)d_in[0];
  const float* prev_hidden = (const float*)d_in[1];
  const float* ccoarse     = (const float*)d_in[2];
  const float* R_w  = (const float*)d_in[3];
  const float* Ic_w = (const float*)d_in[4];
  const float* If_w = (const float*)d_in[5];
  const float* bu   = (const float*)d_in[6];
  const float* br   = (const float*)d_in[7];
  const float* be   = (const float*)d_in[8];
  const float* O1w  = (const float*)d_in[9];
  const float* O1b  = (const float*)d_in[10];
  const float* O2w  = (const float*)d_in[11];
  const float* O2b  = (const float*)d_in[12];
  const float* O3w  = (const float*)d_in[13];
  const float* O3b  = (const float*)d_in[14];
  const float* O4w  = (const float*)d_in[15];
  const float* O4b  = (const float*)d_in[16];

  float* out_coarse = (float*)d_out;
  float* out_fine   = out_coarse + (long)BB * QQ;
  float* hidden     = out_fine + (long)BB * QQ;

  char* ws = (char*)d_ws;
  short* Ah   = (short*)(ws + 0);          // B*H bf16           = 29,360,128 B
  short* Rwh  = (short*)(ws + 29360128);   // NPAD*H bf16        =  5,046,272 B
  short* Rh   = (short*)(ws + 34406400);   // B*2688 bf16        = 88,080,384 B
  short* hidb = (short*)(ws + 122486784);  // B*H bf16           = 29,360,128 B
  short* O1wb = (short*)(ws + 151846912);  // 512*448 bf16
  short* O3wb = (short*)(ws + 152305664);
  short* O2wb = (short*)(ws + 152764416);  // 256*512 bf16
  short* O4wb = (short*)(ws + 153026560);  // end: 153,288,704 B
  // t1/t2 alias the Ah+Rwh region (dead after the R-GEMM)
  short* t1   = (short*)(ws + 0);          // B*512 bf16 = 16,777,216 B
  short* t2   = (short*)(ws + 16777216);   // ends 33,554,432 < 34,406,400 OK

  // casts
  long nAh4 = (long)BB * HH / 4;
  cast4_kernel<<<(int)((nAh4 + 255) / 256), 256, 0, stream>>>(prev_hidden, Ah, nAh4);
  castpad_kernel<<<(NPAD * HH + 255) / 256, 256, 0, stream>>>(R_w, Rwh, 3 * HH, HH, HH, NPAD * HH);
  castpad_kernel<<<(512 * 448 + 255) / 256, 256, 0, stream>>>(O1w, O1wb, 448, 448, 448, 512 * 448);
  castpad_kernel<<<(512 * 448 + 255) / 256, 256, 0, stream>>>(O3w, O3wb, 448, 448, 448, 512 * 448);
  castpad_kernel<<<(256 * 512 + 255) / 256, 256, 0, stream>>>(O2w, O2wb, 256, 448, 512, 256 * 512);
  castpad_kernel<<<(256 * 512 + 255) / 256, 256, 0, stream>>>(O4w, O4wb, 256, 448, 512, 256 * 512);

  // R GEMM: M=B, N=2816 (valid 2688), K=896 -> Rh bf16 (ldc 2688, col-guarded)
  gemm256_bt<<<(BB / 256) * (NPAD / 256), 512, 0, stream>>>(
      Ah, HH, Rwh, HH, Rh, 3 * HH, 3 * HH, HH, NPAD / 256);

  // gates -> hidden (f32 to d_out) + hidb (bf16)
  gates_kernel<<<dim3(7, BB), 128, 0, stream>>>(prev_y, prev_hidden, ccoarse,
                                                Ic_w, If_w, bu, br, be, Rh, hidden, hidb);

  // heads, paired via blockIdx.z
  gemm_bt<EP_RELU_BIAS_BF16><<<dim3(4, BB / 128, 2), 256, 0, stream>>>(
      hidb, hidb + 448, HH, O1wb, O3wb, 448, t1, t2, 512, O1b, O3b, 448, 448);
  gemm_bt<EP_BIAS_F32><<<dim3(2, BB / 128, 2), 256, 0, stream>>>(
      t1, t2, 512, O2wb, O4wb, 512, out_coarse, out_fine, 256, O2b, O4b, 256, 512);
}

// Round 3
// 254.228 us; speedup vs baseline: 1.2691x; 1.0549x over previous
//
#include <hip/hip_runtime.h>
#include <hip/hip_bf16.h>
#include <cstdint>

#define BB 16384
#define HH 896
#define SS 448
#define QQ 256
#define NPAD 2816   // 3H=2688 padded to 11*256

typedef __attribute__((ext_vector_type(4))) float f32x4;
typedef __attribute__((ext_vector_type(8))) short bf16x8;

__device__ __forceinline__ short f2bf(float f){
  union { float f; uint32_t u; } x; x.f = f;
  uint32_t r = (x.u + 0x7fffu + ((x.u >> 16) & 1u)) >> 16;
  return (short)r;
}
__device__ __forceinline__ float bf2f(short b){
  union { uint32_t u; float f; } x; x.u = ((uint32_t)(uint16_t)b) << 16;
  return x.f;
}

// ---------------- cast kernels ----------------
__global__ void cast4_kernel(const float* __restrict__ src, short* __restrict__ dst, long n4){
  long i = (long)blockIdx.x * blockDim.x + threadIdx.x;
  if (i >= n4) return;
  const float4 v = reinterpret_cast<const float4*>(src)[i];
  short4 o; o.x = f2bf(v.x); o.y = f2bf(v.y); o.z = f2bf(v.z); o.w = f2bf(v.w);
  reinterpret_cast<short4*>(dst)[i] = o;
}

__global__ void castpad_kernel(const float* __restrict__ src, short* __restrict__ dst,
                               int srows, int scols, int dcols, int total){
  int i = blockIdx.x * blockDim.x + threadIdx.x;
  if (i >= total) return;
  int r = i / dcols, c = i - r * dcols;
  float v = (r < srows && c < scols) ? src[(long)r * scols + c] : 0.f;
  dst[i] = f2bf(v);
}

// all four O-weight pads in one launch (720,896 elems total)
__global__ void castpadO_kernel(const float* __restrict__ O1w, const float* __restrict__ O3w,
                                const float* __restrict__ O2w, const float* __restrict__ O4w,
                                short* __restrict__ O1b, short* __restrict__ O3b,
                                short* __restrict__ O2b, short* __restrict__ O4b){
  int i = blockIdx.x * 256 + threadIdx.x;
  const int n13 = 512 * 448, n24 = 256 * 512;
  const float* src; short* dst; int srows, scols, dcols, j;
  if (i < n13)                { src = O1w; dst = O1b; srows = 448; scols = 448; dcols = 448; j = i; }
  else if (i < 2 * n13)       { src = O3w; dst = O3b; srows = 448; scols = 448; dcols = 448; j = i - n13; }
  else if (i < 2 * n13 + n24) { src = O2w; dst = O2b; srows = 256; scols = 448; dcols = 512; j = i - 2 * n13; }
  else if (i < 2 * (n13 + n24)) { src = O4w; dst = O4b; srows = 256; scols = 448; dcols = 512; j = i - 2 * n13 - n24; }
  else return;
  int r = j / dcols, c = j - r * dcols;
  float v = (r < srows && c < scols) ? src[(long)r * scols + c] : 0.f;
  dst[j] = f2bf(v);
}

// ================= 256x256 8-phase GEMM (R projection) =================
// Stage issue order A0,B0,B1,A1 gives every vmcnt checkpoint >=2 phases of
// slack vs HBM latency (q1: guard A1(j) issued q3(j-1); q3: guard
// {A0,B0,B1}(j+1), A0 issued q0(j) = 3.5 phases earlier).
__global__ __launch_bounds__(512, 2)
void gemm256_bt(const short* __restrict__ A, int lda,
                const short* __restrict__ Bt, int ldb,
                short* __restrict__ C, int ldc, int Nvalid,
                int K, int nbn)
{
  __shared__ short smem[65536];   // 128 KiB
  const int tid = threadIdx.x;
  const int w  = tid >> 6, ln = tid & 63;
  const int wr = w >> 2,  wc = w & 3;
  const int lr = ln & 15;
  const int lg = ln >> 4;          // k-group 0..3
  const int srow = ln >> 3;        // staging: row within 8-row wave slice
  const int sgc  = (ln & 7) ^ srow; // staging: pre-swizzled source granule

  // bijective XCD swizzle (gridDim.x % 8 == 0)
  int wg = blockIdx.x;
  const int cpx = gridDim.x >> 3;
  wg = (wg & 7) * cpx + (wg >> 3);
  const int bm = wg / nbn, bn = wg - bm * nbn;
  const long m0 = (long)bm * 256, n0 = (long)bn * 256;

  f32x4 acc[8][4] = {};

  auto stage = [&](const short* __restrict__ src, int ld, long rbase, int k0,
                   int lbase /*elem*/, int h) {
#pragma unroll
    for (int i = 0; i < 2; ++i) {
      const int rloc = h * 128 + i * 64 + w * 8;            // wave-uniform
      const short* g = src + (rbase + rloc + srow) * (long)ld + k0 + sgc * 8;
      __builtin_amdgcn_global_load_lds(
          (const __attribute__((address_space(1))) void*)g,
          (__attribute__((address_space(3))) void*)&smem[lbase + rloc * 64],
          16, 0, 0);
    }
  };
  auto rd = [&](int lbase, int r, int ks) -> bf16x8 {
    const int gc = ks * 4 + lg;
    return *reinterpret_cast<const bf16x8*>(&smem[lbase + r * 64 + ((gc ^ (r & 7)) << 3)]);
  };

  const int NT = K >> 6;
  // prologue: tile 0 -> buf 0, order A0,B0,B1,A1
  stage(A,  lda, m0, 0, 0,     0);
  stage(Bt, ldb, n0, 0, 32768, 0);
  stage(Bt, ldb, n0, 0, 32768, 1);
  stage(A,  lda, m0, 0, 0,     1);
  asm volatile("s_waitcnt vmcnt(2)" ::: "memory");   // A0,B0,B1 arrived
  __builtin_amdgcn_s_barrier();
  asm volatile("" ::: "memory");
  __builtin_amdgcn_sched_barrier(0);

  for (int j = 0; j < NT; ++j) {
    const int Ab = (j & 1) * 16384;
    const int Bb = 32768 + (j & 1) * 16384;
    const int An = ((j + 1) & 1) * 16384;
    const int Bn = 32768 + ((j + 1) & 1) * 16384;
    const bool pf = (j + 1 < NT);
    const int k1 = (j + 1) << 6;
    bf16x8 b[4][2];
#pragma unroll
    for (int q = 0; q < 4; ++q) {
      // ---- ds-load register subtiles ----
      bf16x8 a[2][2];
#pragma unroll
      for (int dm = 0; dm < 2; ++dm)
#pragma unroll
        for (int ks = 0; ks < 2; ++ks)
          a[dm][ks] = rd(Ab, q * 64 + dm * 32 + wr * 16 + lr, ks);
      if (q == 0) {
#pragma unroll
        for (int n = 0; n < 4; ++n)
#pragma unroll
          for (int ks = 0; ks < 2; ++ks)
            b[n][ks] = rd(Bb, wc * 64 + n * 16 + lr, ks);
      }
      // ---- stage 1 half-tile of next K-tile (issue order A0,B0,B1,A1) ----
      if (pf) {
        if      (q == 0) stage(A,  lda, m0, k1, An, 0);
        else if (q == 1) stage(Bt, ldb, n0, k1, Bn, 0);
        else if (q == 2) stage(Bt, ldb, n0, k1, Bn, 1);
        else             stage(A,  lda, m0, k1, An, 1);
      }
      asm volatile("" ::: "memory");
      __builtin_amdgcn_s_barrier();
      asm volatile("s_waitcnt lgkmcnt(0)" ::: "memory");
      __builtin_amdgcn_sched_barrier(0);
      // ---- MFMA cluster: one C-quadrant x K=64 (16 MFMA) ----
      __builtin_amdgcn_s_setprio(1);
#pragma unroll
      for (int dm = 0; dm < 2; ++dm)
#pragma unroll
        for (int n = 0; n < 4; ++n)
#pragma unroll
          for (int ks = 0; ks < 2; ++ks)
            acc[2 * q + dm][n] = __builtin_amdgcn_mfma_f32_16x16x32_bf16(
                a[dm][ks], b[n][ks], acc[2 * q + dm][n], 0, 0, 0);
      __builtin_amdgcn_s_setprio(0);
      __builtin_amdgcn_sched_barrier(0);
      // ---- counted vmcnt checkpoints (before the closing barrier) ----
      if (q == 1) {
        // guard A1(j) for phases 2,3 (issued q3 of j-1, 2 phases of slack);
        // outstanding allowed: A0,B0 of j+1
        if (pf) asm volatile("s_waitcnt vmcnt(4)" ::: "memory");
        else    asm volatile("s_waitcnt vmcnt(0)" ::: "memory");
      } else if (q == 3) {
        // guard A0,B0,B1 of j+1 (A0 issued q0(j), 3.5 phases of slack);
        // allow A1(j+1)
        asm volatile("s_waitcnt vmcnt(2)" ::: "memory");
      }
      asm volatile("" ::: "memory");
      __builtin_amdgcn_s_barrier();
      asm volatile("" ::: "memory");
      __builtin_amdgcn_sched_barrier(0);
    }
  }

  // epilogue: C/D layout col=lane&15, row=(lane>>4)*4+reg
  const int lc = ln & 15, rg = lg * 4;
#pragma unroll
  for (int n = 0; n < 4; ++n) {
    long col = n0 + wc * 64 + n * 16 + lc;
    if (col < Nvalid) {
#pragma unroll
      for (int m = 0; m < 8; ++m) {
        long row = m0 + m * 32 + wr * 16 + rg;
#pragma unroll
        for (int reg = 0; reg < 4; ++reg)
          C[(row + reg) * (long)ldc + col] = f2bf(acc[m][n][reg]);
      }
    }
  }
}

// ---------------- 128x128 GEMM (heads), z-paired ----------------
#define EP_RELU_BIAS_BF16 1
#define EP_BIAS_F32 2

template<int EP>
__global__ __launch_bounds__(256)
void gemm_bt(const short* __restrict__ A0, const short* __restrict__ A1, int lda,
             const short* __restrict__ W0, const short* __restrict__ W1, int ldb,
             void* __restrict__ C0v, void* __restrict__ C1v, int ldc,
             const float* __restrict__ bias0, const float* __restrict__ bias1, int nbias,
             int K)
{
  const short* A  = blockIdx.z ? A1 : A0;
  const short* Bt = blockIdx.z ? W1 : W0;
  void* Cv        = blockIdx.z ? C1v : C0v;
  const float* bias = blockIdx.z ? bias1 : bias0;

  __shared__ short As[128 * 64];
  __shared__ short Bs[128 * 64];
  const int tid = threadIdx.x;
  const int wv = tid >> 6, ln = tid & 63;
  const int wr = wv >> 1, wc = wv & 1;
  const long m0 = (long)blockIdx.y * 128;
  const long n0 = (long)blockIdx.x * 128;

  f32x4 acc[4][4] = {};
  const int lr = ln & 15;
  const int lkbase = (ln >> 4) * 8;
  const int e0 = ln * 8;
  for (int k0 = 0; k0 < K; k0 += 64) {
    __syncthreads();
#pragma unroll
    for (int i = 0; i < 4; i++) {
      int chunk = wv * 4 + i;
      int e = chunk * 512 + e0;
      int row = e >> 6, col = e & 63;
      const short* g = A + (m0 + row) * lda + k0 + col;
      __builtin_amdgcn_global_load_lds((const __attribute__((address_space(1))) void*)g,
                                       (__attribute__((address_space(3))) void*)&As[chunk * 512],
                                       16, 0, 0);
    }
#pragma unroll
    for (int i = 0; i < 4; i++) {
      int chunk = wv * 4 + i;
      int e = chunk * 512 + e0;
      int row = e >> 6, col = e & 63;
      const short* g = Bt + (n0 + row) * ldb + k0 + col;
      __builtin_amdgcn_global_load_lds((const __attribute__((address_space(1))) void*)g,
                                       (__attribute__((address_space(3))) void*)&Bs[chunk * 512],
                                       16, 0, 0);
    }
    __syncthreads();
#pragma unroll
    for (int ks = 0; ks < 2; ks++) {
      bf16x8 a[4], b[4];
#pragma unroll
      for (int m = 0; m < 4; m++)
        a[m] = *reinterpret_cast<const bf16x8*>(&As[(wr * 64 + m * 16 + lr) * 64 + ks * 32 + lkbase]);
#pragma unroll
      for (int n = 0; n < 4; n++)
        b[n] = *reinterpret_cast<const bf16x8*>(&Bs[(wc * 64 + n * 16 + lr) * 64 + ks * 32 + lkbase]);
#pragma unroll
      for (int m = 0; m < 4; m++)
#pragma unroll
        for (int n = 0; n < 4; n++)
          acc[m][n] = __builtin_amdgcn_mfma_f32_16x16x32_bf16(a[m], b[n], acc[m][n], 0, 0, 0);
    }
  }

  const int lc = ln & 15;
  const int r4 = (ln >> 4) * 4;
#pragma unroll
  for (int m = 0; m < 4; m++) {
#pragma unroll
    for (int n = 0; n < 4; n++) {
      long col = n0 + wc * 64 + n * 16 + lc;
#pragma unroll
      for (int reg = 0; reg < 4; reg++) {
        long row = m0 + wr * 64 + m * 16 + r4 + reg;
        float v = acc[m][n][reg];
        if (EP == EP_RELU_BIAS_BF16) {
          float bv = (col < nbias) ? bias[col] : 0.f;
          v += bv;
          v = v > 0.f ? v : 0.f;
          ((short*)Cv)[row * ldc + col] = f2bf(v);
        } else {
          v += bias[col];
          ((float*)Cv)[row * ldc + col] = v;
        }
      }
    }
  }
}

// ---------------- gates: vectorized, 8 h per thread ----------------
__global__ __launch_bounds__(256)
void gates_kernel(const float* __restrict__ prev_y,
                  const float* __restrict__ prev_hidden,
                  const float* __restrict__ ccoarse,
                  const float* __restrict__ Icw,
                  const float* __restrict__ Ifw,
                  const float* __restrict__ bu,
                  const float* __restrict__ br,
                  const float* __restrict__ be,
                  const short* __restrict__ Rh,    // [B,2688] bf16
                  float* __restrict__ hid_out,
                  short* __restrict__ hid_bf)
{
  const int v = blockIdx.x * 256 + threadIdx.x;    // 0 .. B*112-1
  const int b = v / 112;
  const int h0 = (v - b * 112) * 8;
  const long rbase = (long)b * (3 * HH);

  const bf16x8 ru8 = *reinterpret_cast<const bf16x8*>(Rh + rbase + h0);
  const bf16x8 rr8 = *reinterpret_cast<const bf16x8*>(Rh + rbase + HH + h0);
  const bf16x8 re8 = *reinterpret_cast<const bf16x8*>(Rh + rbase + 2 * HH + h0);
  const float4* ph4 = reinterpret_cast<const float4*>(prev_hidden + (long)b * HH + h0);
  const float4 pha = ph4[0], phb = ph4[1];
  const float py0 = prev_y[2 * b], py1 = prev_y[2 * b + 1], c0 = ccoarse[b];

  float iu[8], ir[8], ie[8];
  if (h0 < SS) {
    const float4* cu = reinterpret_cast<const float4*>(Icw + 2 * h0);
    const float4* cr = reinterpret_cast<const float4*>(Icw + 2 * (SS + h0));
    const float4* ce = reinterpret_cast<const float4*>(Icw + 2 * (2 * SS + h0));
#pragma unroll
    for (int q = 0; q < 4; ++q) {
      float4 a = cu[q]; iu[2*q] = py0*a.x + py1*a.y; iu[2*q+1] = py0*a.z + py1*a.w;
      float4 r = cr[q]; ir[2*q] = py0*r.x + py1*r.y; ir[2*q+1] = py0*r.z + py1*r.w;
      float4 e = ce[q]; ie[2*q] = py0*e.x + py1*e.y; ie[2*q+1] = py0*e.z + py1*e.w;
    }
  } else {
    const int j0 = h0 - SS;
    const float* fu = Ifw + 3 * j0;
    const float* fr = Ifw + 3 * (SS + j0);
    const float* fe = Ifw + 3 * (2 * SS + j0);
#pragma unroll
    for (int j = 0; j < 8; ++j) {
      iu[j] = py0 * fu[3*j] + py1 * fu[3*j+1] + c0 * fu[3*j+2];
      ir[j] = py0 * fr[3*j] + py1 * fr[3*j+1] + c0 * fr[3*j+2];
      ie[j] = py0 * fe[3*j] + py1 * fe[3*j+1] + c0 * fe[3*j+2];
    }
  }
  const float4* bu4 = reinterpret_cast<const float4*>(bu + h0);
  const float4* br4 = reinterpret_cast<const float4*>(br + h0);
  const float4* be4 = reinterpret_cast<const float4*>(be + h0);
  float buv[8], brv[8], bev[8];
  { float4 a = bu4[0], b2 = bu4[1];
    buv[0]=a.x; buv[1]=a.y; buv[2]=a.z; buv[3]=a.w; buv[4]=b2.x; buv[5]=b2.y; buv[6]=b2.z; buv[7]=b2.w; }
  { float4 a = br4[0], b2 = br4[1];
    brv[0]=a.x; brv[1]=a.y; brv[2]=a.z; brv[3]=a.w; brv[4]=b2.x; brv[5]=b2.y; brv[6]=b2.z; brv[7]=b2.w; }
  { float4 a = be4[0], b2 = be4[1];
    bev[0]=a.x; bev[1]=a.y; bev[2]=a.z; bev[3]=a.w; bev[4]=b2.x; bev[5]=b2.y; bev[6]=b2.z; bev[7]=b2.w; }
  float ph[8] = { pha.x, pha.y, pha.z, pha.w, phb.x, phb.y, phb.z, phb.w };

  float hd[8];
  bf16x8 hb;
#pragma unroll
  for (int j = 0; j < 8; ++j) {
    float u = 1.f / (1.f + __expf(-(bf2f(ru8[j]) + iu[j] + buv[j])));
    float r = 1.f / (1.f + __expf(-(bf2f(rr8[j]) + ir[j] + brv[j])));
    float e = tanhf(r * bf2f(re8[j]) + ie[j] + bev[j]);
    hd[j] = u * ph[j] + (1.f - u) * e;
    hb[j] = f2bf(hd[j]);
  }
  float4* ho = reinterpret_cast<float4*>(hid_out + (long)b * HH + h0);
  ho[0] = make_float4(hd[0], hd[1], hd[2], hd[3]);
  ho[1] = make_float4(hd[4], hd[5], hd[6], hd[7]);
  *reinterpret_cast<bf16x8*>(hid_bf + (long)b * HH + h0) = hb;
}

// ---------------- launch ----------------
extern "C" void kernel_launch(void* const* d_in, const int* in_sizes, int n_in,
                              void* d_out, int out_size, void* d_ws, size_t ws_size,
                              hipStream_t stream)
{
  (void)in_sizes; (void)n_in; (void)out_size; (void)ws_size;
  const float* prev_y      = (const float*)d_in[0];
  const float* prev_hidden = (const float*)d_in[1];
  const float* ccoarse     = (const float*)d_in[2];
  const float* R_w  = (const float*)d_in[3];
  const float* Ic_w = (const float*)d_in[4];
  const float* If_w = (const float*)d_in[5];
  const float* bu   = (const float*)d_in[6];
  const float* br   = (const float*)d_in[7];
  const float* be   = (const float*)d_in[8];
  const float* O1w  = (const float*)d_in[9];
  const float* O1b  = (const float*)d_in[10];
  const float* O2w  = (const float*)d_in[11];
  const float* O2b  = (const float*)d_in[12];
  const float* O3w  = (const float*)d_in[13];
  const float* O3b  = (const float*)d_in[14];
  const float* O4w  = (const float*)d_in[15];
  const float* O4b  = (const float*)d_in[16];

  float* out_coarse = (float*)d_out;
  float* out_fine   = out_coarse + (long)BB * QQ;
  float* hidden     = out_fine + (long)BB * QQ;

  char* ws = (char*)d_ws;
  short* Ah   = (short*)(ws + 0);          // B*H bf16           = 29,360,128 B
  short* Rwh  = (short*)(ws + 29360128);   // NPAD*H bf16        =  5,046,272 B
  short* Rh   = (short*)(ws + 34406400);   // B*2688 bf16        = 88,080,384 B
  short* hidb = (short*)(ws + 122486784);  // B*H bf16           = 29,360,128 B
  short* O1wb = (short*)(ws + 151846912);  // 512*448 bf16
  short* O3wb = (short*)(ws + 152305664);
  short* O2wb = (short*)(ws + 152764416);  // 256*512 bf16
  short* O4wb = (short*)(ws + 153026560);  // end: 153,288,704 B
  // t1/t2 alias the Ah+Rwh region (dead after the R-GEMM)
  short* t1   = (short*)(ws + 0);          // B*512 bf16 = 16,777,216 B
  short* t2   = (short*)(ws + 16777216);   // ends 33,554,432 < 34,406,400 OK

  // casts
  long nAh4 = (long)BB * HH / 4;
  cast4_kernel<<<(int)((nAh4 + 255) / 256), 256, 0, stream>>>(prev_hidden, Ah, nAh4);
  castpad_kernel<<<(NPAD * HH + 255) / 256, 256, 0, stream>>>(R_w, Rwh, 3 * HH, HH, HH, NPAD * HH);
  castpadO_kernel<<<(2 * (512 * 448 + 256 * 512) + 255) / 256, 256, 0, stream>>>(
      O1w, O3w, O2w, O4w, O1wb, O3wb, O2wb, O4wb);

  // R GEMM: M=B, N=2816 (valid 2688), K=896 -> Rh bf16 (ldc 2688, col-guarded)
  gemm256_bt<<<(BB / 256) * (NPAD / 256), 512, 0, stream>>>(
      Ah, HH, Rwh, HH, Rh, 3 * HH, 3 * HH, HH, NPAD / 256);

  // gates -> hidden (f32 to d_out) + hidb (bf16)
  gates_kernel<<<BB * 112 / 256, 256, 0, stream>>>(prev_y, prev_hidden, ccoarse,
                                                   Ic_w, If_w, bu, br, be, Rh, hidden, hidb);

  // heads, paired via blockIdx.z
  gemm_bt<EP_RELU_BIAS_BF16><<<dim3(4, BB / 128, 2), 256, 0, stream>>>(
      hidb, hidb + 448, HH, O1wb, O3wb, 448, t1, t2, 512, O1b, O3b, 448, 448);
  gemm_bt<EP_BIAS_F32><<<dim3(2, BB / 128, 2), 256, 0, stream>>>(
      t1, t2, 512, O2wb, O4wb, 512, out_coarse, out_fine, 256, O2b, O4b, 256, 512);
}

// Round 4
// 252.138 us; speedup vs baseline: 1.2796x; 1.0083x over previous
//
#include <hip/hip_runtime.h>
#include <hip/hip_bf16.h>
#include <cstdint>

#define BB 16384
#define HH 896
#define SS 448
#define QQ 256
#define NPAD 2816   // 3H=2688 padded to 11*256

typedef __attribute__((ext_vector_type(4))) float f32x4;
typedef __attribute__((ext_vector_type(8))) short bf16x8;

__device__ __forceinline__ short f2bf(float f){
  union { float f; uint32_t u; } x; x.f = f;
  uint32_t r = (x.u + 0x7fffu + ((x.u >> 16) & 1u)) >> 16;
  return (short)r;
}
__device__ __forceinline__ float bf2f(short b){
  union { uint32_t u; float f; } x; x.u = ((uint32_t)(uint16_t)b) << 16;
  return x.f;
}

// ---------------- cast kernels ----------------
__global__ void cast4_kernel(const float* __restrict__ src, short* __restrict__ dst, long n4){
  long i = (long)blockIdx.x * blockDim.x + threadIdx.x;
  if (i >= n4) return;
  const float4 v = reinterpret_cast<const float4*>(src)[i];
  short4 o; o.x = f2bf(v.x); o.y = f2bf(v.y); o.z = f2bf(v.z); o.w = f2bf(v.w);
  reinterpret_cast<short4*>(dst)[i] = o;
}

__global__ void castpad_kernel(const float* __restrict__ src, short* __restrict__ dst,
                               int srows, int scols, int dcols, int total){
  int i = blockIdx.x * blockDim.x + threadIdx.x;
  if (i >= total) return;
  int r = i / dcols, c = i - r * dcols;
  float v = (r < srows && c < scols) ? src[(long)r * scols + c] : 0.f;
  dst[i] = f2bf(v);
}

// all four O-weight pads in one launch (720,896 elems total)
__global__ void castpadO_kernel(const float* __restrict__ O1w, const float* __restrict__ O3w,
                                const float* __restrict__ O2w, const float* __restrict__ O4w,
                                short* __restrict__ O1b, short* __restrict__ O3b,
                                short* __restrict__ O2b, short* __restrict__ O4b){
  int i = blockIdx.x * 256 + threadIdx.x;
  const int n13 = 512 * 448, n24 = 256 * 512;
  const float* src; short* dst; int srows, scols, dcols, j;
  if (i < n13)                { src = O1w; dst = O1b; srows = 448; scols = 448; dcols = 448; j = i; }
  else if (i < 2 * n13)       { src = O3w; dst = O3b; srows = 448; scols = 448; dcols = 448; j = i - n13; }
  else if (i < 2 * n13 + n24) { src = O2w; dst = O2b; srows = 256; scols = 448; dcols = 512; j = i - 2 * n13; }
  else if (i < 2 * (n13 + n24)) { src = O4w; dst = O4b; srows = 256; scols = 448; dcols = 512; j = i - 2 * n13 - n24; }
  else return;
  int r = j / dcols, c = j - r * dcols;
  float v = (r < srows && c < scols) ? src[(long)r * scols + c] : 0.f;
  dst[j] = f2bf(v);
}

// ================= 256x256 8-phase GEMM (R projection) =================
// All 8 loads of tile j+1 are issued at q0 of tile j (buf^1 is free the whole
// tile). Guards: q1 vmcnt(8) drains A1(j) (issued q0(j-1), 5 phases earlier);
// q3 vmcnt(2) drains A0,B0,B1(j+1) (issued q0(j), 3 phases earlier), leaving
// A1(j+1). Every guard is per-wave-then-barrier provable with >=3 phases of
// slack vs ~900cyc HBM latency.
__global__ __launch_bounds__(512, 2)
void gemm256_bt(const short* __restrict__ A, int lda,
                const short* __restrict__ Bt, int ldb,
                short* __restrict__ C, int ldc, int Nvalid,
                int K, int nbn)
{
  __shared__ short smem[65536];   // 128 KiB
  const int tid = threadIdx.x;
  const int w  = tid >> 6, ln = tid & 63;
  const int wr = w >> 2,  wc = w & 3;
  const int lr = ln & 15;
  const int lg = ln >> 4;          // k-group 0..3
  const int srow = ln >> 3;        // staging: row within 8-row wave slice
  const int sgc  = (ln & 7) ^ srow; // staging: pre-swizzled source granule

  // bijective XCD swizzle (gridDim.x % 8 == 0)
  int wg = blockIdx.x;
  const int cpx = gridDim.x >> 3;
  wg = (wg & 7) * cpx + (wg >> 3);
  const int bm = wg / nbn, bn = wg - bm * nbn;
  const long m0 = (long)bm * 256, n0 = (long)bn * 256;

  f32x4 acc[8][4] = {};

  auto stage = [&](const short* __restrict__ src, int ld, long rbase, int k0,
                   int lbase /*elem*/, int h) {
#pragma unroll
    for (int i = 0; i < 2; ++i) {
      const int rloc = h * 128 + i * 64 + w * 8;            // wave-uniform
      const short* g = src + (rbase + rloc + srow) * (long)ld + k0 + sgc * 8;
      __builtin_amdgcn_global_load_lds(
          (const __attribute__((address_space(1))) void*)g,
          (__attribute__((address_space(3))) void*)&smem[lbase + rloc * 64],
          16, 0, 0);
    }
  };
  auto rd = [&](int lbase, int r, int ks) -> bf16x8 {
    const int gc = ks * 4 + lg;
    return *reinterpret_cast<const bf16x8*>(&smem[lbase + r * 64 + ((gc ^ (r & 7)) << 3)]);
  };

  const int NT = K >> 6;
  // prologue: tile 0 -> buf 0, issue order A0,B0,B1,A1
  stage(A,  lda, m0, 0, 0,     0);
  stage(Bt, ldb, n0, 0, 32768, 0);
  stage(Bt, ldb, n0, 0, 32768, 1);
  stage(A,  lda, m0, 0, 0,     1);
  asm volatile("s_waitcnt vmcnt(2)" ::: "memory");   // A0,B0,B1 arrived
  __builtin_amdgcn_s_barrier();
  asm volatile("" ::: "memory");
  __builtin_amdgcn_sched_barrier(0);

  for (int j = 0; j < NT; ++j) {
    const int Ab = (j & 1) * 16384;
    const int Bb = 32768 + (j & 1) * 16384;
    const int An = ((j + 1) & 1) * 16384;
    const int Bn = 32768 + ((j + 1) & 1) * 16384;
    const bool pf = (j + 1 < NT);
    const int k1 = (j + 1) << 6;
    bf16x8 b[4][2];
#pragma unroll
    for (int q = 0; q < 4; ++q) {
      // ---- ds-load register subtiles ----
      bf16x8 a[2][2];
#pragma unroll
      for (int dm = 0; dm < 2; ++dm)
#pragma unroll
        for (int ks = 0; ks < 2; ++ks)
          a[dm][ks] = rd(Ab, q * 64 + dm * 32 + wr * 16 + lr, ks);
      if (q == 0) {
#pragma unroll
        for (int n = 0; n < 4; ++n)
#pragma unroll
          for (int ks = 0; ks < 2; ++ks)
            b[n][ks] = rd(Bb, wc * 64 + n * 16 + lr, ks);
        // ---- issue ALL of tile j+1's staging here (buf^1 free all tile) ----
        if (pf) {
          stage(A,  lda, m0, k1, An, 0);
          stage(Bt, ldb, n0, k1, Bn, 0);
          stage(Bt, ldb, n0, k1, Bn, 1);
          stage(A,  lda, m0, k1, An, 1);
        }
      }
      asm volatile("" ::: "memory");
      __builtin_amdgcn_s_barrier();
      asm volatile("s_waitcnt lgkmcnt(0)" ::: "memory");
      __builtin_amdgcn_sched_barrier(0);
      // ---- MFMA cluster: one C-quadrant x K=64 (16 MFMA) ----
      __builtin_amdgcn_s_setprio(1);
#pragma unroll
      for (int dm = 0; dm < 2; ++dm)
#pragma unroll
        for (int n = 0; n < 4; ++n)
#pragma unroll
          for (int ks = 0; ks < 2; ++ks)
            acc[2 * q + dm][n] = __builtin_amdgcn_mfma_f32_16x16x32_bf16(
                a[dm][ks], b[n][ks], acc[2 * q + dm][n], 0, 0, 0);
      __builtin_amdgcn_s_setprio(0);
      __builtin_amdgcn_sched_barrier(0);
      // ---- counted vmcnt checkpoints (before the closing barrier) ----
      if (q == 1) {
        // guard A1(j) (issued q0 of j-1, 5 phases earlier) for phases 2,3;
        // outstanding allowed: the 8 loads of tile j+1 issued at q0(j)
        if (pf) asm volatile("s_waitcnt vmcnt(8)" ::: "memory");
        else    asm volatile("s_waitcnt vmcnt(0)" ::: "memory");
      } else if (q == 3) {
        // guard A0,B0,B1(j+1) (issued q0(j), 3 phases earlier); allow A1(j+1)
        asm volatile("s_waitcnt vmcnt(2)" ::: "memory");
      }
      asm volatile("" ::: "memory");
      __builtin_amdgcn_s_barrier();
      asm volatile("" ::: "memory");
      __builtin_amdgcn_sched_barrier(0);
    }
  }

  // ---- epilogue: LDS bounce for coalesced bf16x8 stores ----
  // (last phase's closing barrier guarantees all waves finished LDS reads;
  //  no DMA outstanding: last tile had pf=false)
#pragma unroll
  for (int n = 0; n < 4; ++n) {
    const int col = wc * 64 + n * 16 + lr;
#pragma unroll
    for (int m = 0; m < 8; ++m) {
      const int row = m * 32 + wr * 16 + lg * 4;
#pragma unroll
      for (int reg = 0; reg < 4; ++reg)
        smem[(row + reg) * 256 + col] = f2bf(acc[m][n][reg]);
    }
  }
  __builtin_amdgcn_s_barrier();
  const int rt = tid >> 5;          // 16 rows per pass
  const int ct = (tid & 31) * 8;    // 32 lanes x 8 cols = 256
  const long colg = n0 + ct;
  if (colg < Nvalid) {
#pragma unroll
    for (int p = 0; p < 16; ++p) {
      const int row = p * 16 + rt;
      bf16x8 v = *reinterpret_cast<const bf16x8*>(&smem[row * 256 + ct]);
      *reinterpret_cast<bf16x8*>(&C[(m0 + row) * (long)ldc + colg]) = v;
    }
  }
}

// ---------------- 128x128 GEMM (heads), z-paired ----------------
#define EP_RELU_BIAS_BF16 1
#define EP_BIAS_F32 2

template<int EP>
__global__ __launch_bounds__(256)
void gemm_bt(const short* __restrict__ A0, const short* __restrict__ A1, int lda,
             const short* __restrict__ W0, const short* __restrict__ W1, int ldb,
             void* __restrict__ C0v, void* __restrict__ C1v, int ldc,
             const float* __restrict__ bias0, const float* __restrict__ bias1, int nbias,
             int K)
{
  const short* A  = blockIdx.z ? A1 : A0;
  const short* Bt = blockIdx.z ? W1 : W0;
  void* Cv        = blockIdx.z ? C1v : C0v;
  const float* bias = blockIdx.z ? bias1 : bias0;

  __shared__ short As[128 * 64];
  __shared__ short Bs[128 * 64];
  const int tid = threadIdx.x;
  const int wv = tid >> 6, ln = tid & 63;
  const int wr = wv >> 1, wc = wv & 1;
  const long m0 = (long)blockIdx.y * 128;
  const long n0 = (long)blockIdx.x * 128;

  f32x4 acc[4][4] = {};
  const int lr = ln & 15;
  const int lkbase = (ln >> 4) * 8;
  const int e0 = ln * 8;
  for (int k0 = 0; k0 < K; k0 += 64) {
    __syncthreads();
#pragma unroll
    for (int i = 0; i < 4; i++) {
      int chunk = wv * 4 + i;
      int e = chunk * 512 + e0;
      int row = e >> 6, col = e & 63;
      const short* g = A + (m0 + row) * lda + k0 + col;
      __builtin_amdgcn_global_load_lds((const __attribute__((address_space(1))) void*)g,
                                       (__attribute__((address_space(3))) void*)&As[chunk * 512],
                                       16, 0, 0);
    }
#pragma unroll
    for (int i = 0; i < 4; i++) {
      int chunk = wv * 4 + i;
      int e = chunk * 512 + e0;
      int row = e >> 6, col = e & 63;
      const short* g = Bt + (n0 + row) * ldb + k0 + col;
      __builtin_amdgcn_global_load_lds((const __attribute__((address_space(1))) void*)g,
                                       (__attribute__((address_space(3))) void*)&Bs[chunk * 512],
                                       16, 0, 0);
    }
    __syncthreads();
#pragma unroll
    for (int ks = 0; ks < 2; ks++) {
      bf16x8 a[4], b[4];
#pragma unroll
      for (int m = 0; m < 4; m++)
        a[m] = *reinterpret_cast<const bf16x8*>(&As[(wr * 64 + m * 16 + lr) * 64 + ks * 32 + lkbase]);
#pragma unroll
      for (int n = 0; n < 4; n++)
        b[n] = *reinterpret_cast<const bf16x8*>(&Bs[(wc * 64 + n * 16 + lr) * 64 + ks * 32 + lkbase]);
#pragma unroll
      for (int m = 0; m < 4; m++)
#pragma unroll
        for (int n = 0; n < 4; n++)
          acc[m][n] = __builtin_amdgcn_mfma_f32_16x16x32_bf16(a[m], b[n], acc[m][n], 0, 0, 0);
    }
  }

  const int lc = ln & 15;
  const int r4 = (ln >> 4) * 4;
#pragma unroll
  for (int m = 0; m < 4; m++) {
#pragma unroll
    for (int n = 0; n < 4; n++) {
      long col = n0 + wc * 64 + n * 16 + lc;
#pragma unroll
      for (int reg = 0; reg < 4; reg++) {
        long row = m0 + wr * 64 + m * 16 + r4 + reg;
        float v = acc[m][n][reg];
        if (EP == EP_RELU_BIAS_BF16) {
          float bv = (col < nbias) ? bias[col] : 0.f;
          v += bv;
          v = v > 0.f ? v : 0.f;
          ((short*)Cv)[row * ldc + col] = f2bf(v);
        } else {
          v += bias[col];
          ((float*)Cv)[row * ldc + col] = v;
        }
      }
    }
  }
}

// ---------------- gates: vectorized, 8 h per thread ----------------
__global__ __launch_bounds__(256)
void gates_kernel(const float* __restrict__ prev_y,
                  const float* __restrict__ prev_hidden,
                  const float* __restrict__ ccoarse,
                  const float* __restrict__ Icw,
                  const float* __restrict__ Ifw,
                  const float* __restrict__ bu,
                  const float* __restrict__ br,
                  const float* __restrict__ be,
                  const short* __restrict__ Rh,    // [B,2688] bf16
                  float* __restrict__ hid_out,
                  short* __restrict__ hid_bf)
{
  const int v = blockIdx.x * 256 + threadIdx.x;    // 0 .. B*112-1
  const int b = v / 112;
  const int h0 = (v - b * 112) * 8;
  const long rbase = (long)b * (3 * HH);

  const bf16x8 ru8 = *reinterpret_cast<const bf16x8*>(Rh + rbase + h0);
  const bf16x8 rr8 = *reinterpret_cast<const bf16x8*>(Rh + rbase + HH + h0);
  const bf16x8 re8 = *reinterpret_cast<const bf16x8*>(Rh + rbase + 2 * HH + h0);
  const float4* ph4 = reinterpret_cast<const float4*>(prev_hidden + (long)b * HH + h0);
  const float4 pha = ph4[0], phb = ph4[1];
  const float py0 = prev_y[2 * b], py1 = prev_y[2 * b + 1], c0 = ccoarse[b];

  float iu[8], ir[8], ie[8];
  if (h0 < SS) {
    const float4* cu = reinterpret_cast<const float4*>(Icw + 2 * h0);
    const float4* cr = reinterpret_cast<const float4*>(Icw + 2 * (SS + h0));
    const float4* ce = reinterpret_cast<const float4*>(Icw + 2 * (2 * SS + h0));
#pragma unroll
    for (int q = 0; q < 4; ++q) {
      float4 a = cu[q]; iu[2*q] = py0*a.x + py1*a.y; iu[2*q+1] = py0*a.z + py1*a.w;
      float4 r = cr[q]; ir[2*q] = py0*r.x + py1*r.y; ir[2*q+1] = py0*r.z + py1*r.w;
      float4 e = ce[q]; ie[2*q] = py0*e.x + py1*e.y; ie[2*q+1] = py0*e.z + py1*e.w;
    }
  } else {
    const int j0 = h0 - SS;
    const float* fu = Ifw + 3 * j0;
    const float* fr = Ifw + 3 * (SS + j0);
    const float* fe = Ifw + 3 * (2 * SS + j0);
#pragma unroll
    for (int j = 0; j < 8; ++j) {
      iu[j] = py0 * fu[3*j] + py1 * fu[3*j+1] + c0 * fu[3*j+2];
      ir[j] = py0 * fr[3*j] + py1 * fr[3*j+1] + c0 * fr[3*j+2];
      ie[j] = py0 * fe[3*j] + py1 * fe[3*j+1] + c0 * fe[3*j+2];
    }
  }
  const float4* bu4 = reinterpret_cast<const float4*>(bu + h0);
  const float4* br4 = reinterpret_cast<const float4*>(br + h0);
  const float4* be4 = reinterpret_cast<const float4*>(be + h0);
  float buv[8], brv[8], bev[8];
  { float4 a = bu4[0], b2 = bu4[1];
    buv[0]=a.x; buv[1]=a.y; buv[2]=a.z; buv[3]=a.w; buv[4]=b2.x; buv[5]=b2.y; buv[6]=b2.z; buv[7]=b2.w; }
  { float4 a = br4[0], b2 = br4[1];
    brv[0]=a.x; brv[1]=a.y; brv[2]=a.z; brv[3]=a.w; brv[4]=b2.x; brv[5]=b2.y; brv[6]=b2.z; brv[7]=b2.w; }
  { float4 a = be4[0], b2 = be4[1];
    bev[0]=a.x; bev[1]=a.y; bev[2]=a.z; bev[3]=a.w; bev[4]=b2.x; bev[5]=b2.y; bev[6]=b2.z; bev[7]=b2.w; }
  float ph[8] = { pha.x, pha.y, pha.z, pha.w, phb.x, phb.y, phb.z, phb.w };

  float hd[8];
  bf16x8 hb;
#pragma unroll
  for (int j = 0; j < 8; ++j) {
    float u = 1.f / (1.f + __expf(-(bf2f(ru8[j]) + iu[j] + buv[j])));
    float r = 1.f / (1.f + __expf(-(bf2f(rr8[j]) + ir[j] + brv[j])));
    float e = tanhf(r * bf2f(re8[j]) + ie[j] + bev[j]);
    hd[j] = u * ph[j] + (1.f - u) * e;
    hb[j] = f2bf(hd[j]);
  }
  float4* ho = reinterpret_cast<float4*>(hid_out + (long)b * HH + h0);
  ho[0] = make_float4(hd[0], hd[1], hd[2], hd[3]);
  ho[1] = make_float4(hd[4], hd[5], hd[6], hd[7]);
  *reinterpret_cast<bf16x8*>(hid_bf + (long)b * HH + h0) = hb;
}

// ---------------- launch ----------------
extern "C" void kernel_launch(void* const* d_in, const int* in_sizes, int n_in,
                              void* d_out, int out_size, void* d_ws, size_t ws_size,
                              hipStream_t stream)
{
  (void)in_sizes; (void)n_in; (void)out_size; (void)ws_size;
  const float* prev_y      = (const float*)d_in[0];
  const float* prev_hidden = (const float*)d_in[1];
  const float* ccoarse     = (const float*)d_in[2];
  const float* R_w  = (const float*)d_in[3];
  const float* Ic_w = (const float*)d_in[4];
  const float* If_w = (const float*)d_in[5];
  const float* bu   = (const float*)d_in[6];
  const float* br   = (const float*)d_in[7];
  const float* be   = (const float*)d_in[8];
  const float* O1w  = (const float*)d_in[9];
  const float* O1b  = (const float*)d_in[10];
  const float* O2w  = (const float*)d_in[11];
  const float* O2b  = (const float*)d_in[12];
  const float* O3w  = (const float*)d_in[13];
  const float* O3b  = (const float*)d_in[14];
  const float* O4w  = (const float*)d_in[15];
  const float* O4b  = (const float*)d_in[16];

  float* out_coarse = (float*)d_out;
  float* out_fine   = out_coarse + (long)BB * QQ;
  float* hidden     = out_fine + (long)BB * QQ;

  char* ws = (char*)d_ws;
  short* Ah   = (short*)(ws + 0);          // B*H bf16           = 29,360,128 B
  short* Rwh  = (short*)(ws + 29360128);   // NPAD*H bf16        =  5,046,272 B
  short* Rh   = (short*)(ws + 34406400);   // B*2688 bf16        = 88,080,384 B
  short* hidb = (short*)(ws + 122486784);  // B*H bf16           = 29,360,128 B
  short* O1wb = (short*)(ws + 151846912);  // 512*448 bf16
  short* O3wb = (short*)(ws + 152305664);
  short* O2wb = (short*)(ws + 152764416);  // 256*512 bf16
  short* O4wb = (short*)(ws + 153026560);  // end: 153,288,704 B
  // t1/t2 alias the Ah+Rwh region (dead after the R-GEMM)
  short* t1   = (short*)(ws + 0);          // B*512 bf16 = 16,777,216 B
  short* t2   = (short*)(ws + 16777216);   // ends 33,554,432 < 34,406,400 OK

  // casts
  long nAh4 = (long)BB * HH / 4;
  cast4_kernel<<<(int)((nAh4 + 255) / 256), 256, 0, stream>>>(prev_hidden, Ah, nAh4);
  castpad_kernel<<<(NPAD * HH + 255) / 256, 256, 0, stream>>>(R_w, Rwh, 3 * HH, HH, HH, NPAD * HH);
  castpadO_kernel<<<(2 * (512 * 448 + 256 * 512) + 255) / 256, 256, 0, stream>>>(
      O1w, O3w, O2w, O4w, O1wb, O3wb, O2wb, O4wb);

  // R GEMM: M=B, N=2816 (valid 2688), K=896 -> Rh bf16 (ldc 2688, col-guarded)
  gemm256_bt<<<(BB / 256) * (NPAD / 256), 512, 0, stream>>>(
      Ah, HH, Rwh, HH, Rh, 3 * HH, 3 * HH, HH, NPAD / 256);

  // gates -> hidden (f32 to d_out) + hidb (bf16)
  gates_kernel<<<BB * 112 / 256, 256, 0, stream>>>(prev_y, prev_hidden, ccoarse,
                                                   Ic_w, If_w, bu, br, be, Rh, hidden, hidb);

  // heads, paired via blockIdx.z
  gemm_bt<EP_RELU_BIAS_BF16><<<dim3(4, BB / 128, 2), 256, 0, stream>>>(
      hidb, hidb + 448, HH, O1wb, O3wb, 448, t1, t2, 512, O1b, O3b, 448, 448);
  gemm_bt<EP_BIAS_F32><<<dim3(2, BB / 128, 2), 256, 0, stream>>>(
      t1, t2, 512, O2wb, O4wb, 512, out_coarse, out_fine, 256, O2b, O4b, 256, 512);
}

// Round 5
// 214.823 us; speedup vs baseline: 1.5019x; 1.1737x over previous
//
#include <hip/hip_runtime.h>
#include <hip/hip_bf16.h>
#include <cstdint>

#define BB 16384
#define HH 896
#define SS 448
#define QQ 256
#define NPAD 2816   // 3H=2688 padded to 11*256

typedef __attribute__((ext_vector_type(4))) float f32x4;
typedef __attribute__((ext_vector_type(8))) short bf16x8;

__device__ __forceinline__ short f2bf(float f){
  union { float f; uint32_t u; } x; x.f = f;
  uint32_t r = (x.u + 0x7fffu + ((x.u >> 16) & 1u)) >> 16;
  return (short)r;
}
__device__ __forceinline__ float bf2f(short b){
  union { uint32_t u; float f; } x; x.u = ((uint32_t)(uint16_t)b) << 16;
  return x.f;
}

// ---------------- unified cast kernel (one launch) ----------------
// unit = 4 consecutive elements. Ranges:
//   [0, 3670016)                 Ah   <- prev_hidden (copy)
//   [3670016, 4272128)           Rwh  <- R_w (copy, 602112 units)
//   [4272128, 4300800)           Rwh pad rows -> zero (28672 units)
//   [4300800, 4358144)           O1wb: unit<50176 copy else zero
//   [4358144, 4415488)           O3wb: same
//   [4415488, 4448256)           O2wb: per-row pad 448->512
//   [4448256, 4481024)           O4wb: per-row pad 448->512
__global__ __launch_bounds__(256)
void castall_kernel(const float* __restrict__ ph, short* __restrict__ Ah,
                    const float* __restrict__ Rw, short* __restrict__ Rwh,
                    const float* __restrict__ O1w, short* __restrict__ O1b,
                    const float* __restrict__ O3w, short* __restrict__ O3b,
                    const float* __restrict__ O2w, short* __restrict__ O2b,
                    const float* __restrict__ O4w, short* __restrict__ O4b)
{
  int u = blockIdx.x * 256 + threadIdx.x;
  auto cp4 = [](short* d, const float* s, int jd, int js){
    float4 v = reinterpret_cast<const float4*>(s)[js];
    short4 o; o.x = f2bf(v.x); o.y = f2bf(v.y); o.z = f2bf(v.z); o.w = f2bf(v.w);
    reinterpret_cast<short4*>(d)[jd] = o;
  };
  auto z4 = [](short* d, int jd){
    short4 o; o.x = 0; o.y = 0; o.z = 0; o.w = 0;
    reinterpret_cast<short4*>(d)[jd] = o;
  };
  if (u < 3670016) { cp4(Ah, ph, u, u); return; }
  u -= 3670016;
  if (u < 602112) { cp4(Rwh, Rw, u, u); return; }
  u -= 602112;
  if (u < 28672) { z4(Rwh, 602112 + u); return; }
  u -= 28672;
  if (u < 57344) { if (u < 50176) cp4(O1b, O1w, u, u); else z4(O1b, u); return; }
  u -= 57344;
  if (u < 57344) { if (u < 50176) cp4(O3b, O3w, u, u); else z4(O3b, u); return; }
  u -= 57344;
  if (u < 32768) {
    int r = u >> 7, c4 = u & 127;
    if (c4 < 112) cp4(O2b, O2w, u, r * 112 + c4); else z4(O2b, u);
    return;
  }
  u -= 32768;
  if (u < 32768) {
    int r = u >> 7, c4 = u & 127;
    if (c4 < 112) cp4(O4b, O4w, u, r * 112 + c4); else z4(O4b, u);
    return;
  }
}

// ================= 256x256 phase-interleaved GEMM =================
// Guard chains (the only barriers kept):
//   q1: vmcnt(8)+barrier  -> A1(j) complete before q2/q3 reads
//   q3: vmcnt(2)+barrier  -> A0,B0,B1(j+1) complete before next tile's reads
// All other sync removed: each wave's ds_reads are its own (lgkmcnt local).
// EP 0: bf16 store via LDS bounce (R projection)
// EP 1: bias+relu -> bf16 via LDS bounce (head layer 1)
// EP 2: bias -> f32 direct store (head layer 2; 64B-contiguous fragments)
template<int EP>
__global__ __launch_bounds__(512, 2)
void gemm256_bt(const short* __restrict__ A0p, const short* __restrict__ A1p, int lda,
                const short* __restrict__ B0p, const short* __restrict__ B1p, int ldb,
                void* __restrict__ C0p, void* __restrict__ C1p, int ldc,
                const float* __restrict__ bias0, const float* __restrict__ bias1, int nbias,
                int Nvalid, int K, int nbn)
{
  const short* A  = blockIdx.z ? A1p : A0p;
  const short* Bt = blockIdx.z ? B1p : B0p;
  void* Cv        = blockIdx.z ? C1p : C0p;
  const float* bias = blockIdx.z ? bias1 : bias0;

  __shared__ short smem[65536];   // 128 KiB
  const int tid = threadIdx.x;
  const int w  = tid >> 6, ln = tid & 63;
  const int wr = w >> 2,  wc = w & 3;
  const int lr = ln & 15;
  const int lg = ln >> 4;          // k-group 0..3
  const int srow = ln >> 3;        // staging: row within 8-row wave slice
  const int sgc  = (ln & 7) ^ srow; // staging: pre-swizzled source granule

  // bijective XCD swizzle (gridDim.x % 8 == 0)
  int wg = blockIdx.x;
  const int cpx = gridDim.x >> 3;
  wg = (wg & 7) * cpx + (wg >> 3);
  const int bm = wg / nbn, bn = wg - bm * nbn;
  const long m0 = (long)bm * 256, n0 = (long)bn * 256;

  f32x4 acc[8][4] = {};

  auto stage = [&](const short* __restrict__ src, int ld, long rbase, int k0,
                   int lbase /*elem*/, int h) {
#pragma unroll
    for (int i = 0; i < 2; ++i) {
      const int rloc = h * 128 + i * 64 + w * 8;            // wave-uniform
      const short* g = src + (rbase + rloc + srow) * (long)ld + k0 + sgc * 8;
      __builtin_amdgcn_global_load_lds(
          (const __attribute__((address_space(1))) void*)g,
          (__attribute__((address_space(3))) void*)&smem[lbase + rloc * 64],
          16, 0, 0);
    }
  };
  auto rd = [&](int lbase, int r, int ks) -> bf16x8 {
    const int gc = ks * 4 + lg;
    return *reinterpret_cast<const bf16x8*>(&smem[lbase + r * 64 + ((gc ^ (r & 7)) << 3)]);
  };

  const int NT = K >> 6;
  // prologue: tile 0 -> buf 0, issue order A0,B0,B1,A1
  stage(A,  lda, m0, 0, 0,     0);
  stage(Bt, ldb, n0, 0, 32768, 0);
  stage(Bt, ldb, n0, 0, 32768, 1);
  stage(A,  lda, m0, 0, 0,     1);
  asm volatile("s_waitcnt vmcnt(2)" ::: "memory");   // A0,B0,B1 arrived
  __builtin_amdgcn_s_barrier();
  asm volatile("" ::: "memory");
  __builtin_amdgcn_sched_barrier(0);

  for (int j = 0; j < NT; ++j) {
    const int Ab = (j & 1) * 16384;
    const int Bb = 32768 + (j & 1) * 16384;
    const int An = ((j + 1) & 1) * 16384;
    const int Bn = 32768 + ((j + 1) & 1) * 16384;
    const bool pf = (j + 1 < NT);
    const int k1 = (j + 1) << 6;
    bf16x8 b[4][2];
#pragma unroll
    for (int q = 0; q < 4; ++q) {
      // ---- ds-load register subtiles (each wave reads only for itself) ----
      bf16x8 a[2][2];
#pragma unroll
      for (int dm = 0; dm < 2; ++dm)
#pragma unroll
        for (int ks = 0; ks < 2; ++ks)
          a[dm][ks] = rd(Ab, q * 64 + dm * 32 + wr * 16 + lr, ks);
      if (q == 0) {
#pragma unroll
        for (int n = 0; n < 4; ++n)
#pragma unroll
          for (int ks = 0; ks < 2; ++ks)
            b[n][ks] = rd(Bb, wc * 64 + n * 16 + lr, ks);
        // ---- issue ALL of tile j+1's staging (buf^1 free all tile) ----
        if (pf) {
          stage(A,  lda, m0, k1, An, 0);
          stage(Bt, ldb, n0, k1, Bn, 0);
          stage(Bt, ldb, n0, k1, Bn, 1);
          stage(A,  lda, m0, k1, An, 1);
        }
      }
      asm volatile("s_waitcnt lgkmcnt(0)" ::: "memory");
      __builtin_amdgcn_sched_barrier(0);
      // ---- MFMA cluster: one C-quadrant x K=64 (16 MFMA) ----
      __builtin_amdgcn_s_setprio(1);
#pragma unroll
      for (int dm = 0; dm < 2; ++dm)
#pragma unroll
        for (int n = 0; n < 4; ++n)
#pragma unroll
          for (int ks = 0; ks < 2; ++ks)
            acc[2 * q + dm][n] = __builtin_amdgcn_mfma_f32_16x16x32_bf16(
                a[dm][ks], b[n][ks], acc[2 * q + dm][n], 0, 0, 0);
      __builtin_amdgcn_s_setprio(0);
      __builtin_amdgcn_sched_barrier(0);
      // ---- guard-chain barriers only ----
      if (q == 1) {
        // A1(j) must be complete before q2/q3 reads (all waves' slices)
        if (pf) asm volatile("s_waitcnt vmcnt(8)" ::: "memory");
        else    asm volatile("s_waitcnt vmcnt(0)" ::: "memory");
        __builtin_amdgcn_s_barrier();
        asm volatile("" ::: "memory");
        __builtin_amdgcn_sched_barrier(0);
      } else if (q == 3) {
        // A0,B0,B1(j+1) complete before next tile's q0/q1 reads
        asm volatile("s_waitcnt vmcnt(2)" ::: "memory");
        __builtin_amdgcn_s_barrier();
        asm volatile("" ::: "memory");
        __builtin_amdgcn_sched_barrier(0);
      }
    }
  }

  if (EP == 2) {
    // direct f32 store: 16-lane fragments are 64B-contiguous, no write-amp
    const int lc = ln & 15, rg = lg * 4;
#pragma unroll
    for (int n = 0; n < 4; ++n) {
      const long col = n0 + wc * 64 + n * 16 + lc;
      const float bv = bias[col];
#pragma unroll
      for (int m = 0; m < 8; ++m) {
        const long row = m0 + m * 32 + wr * 16 + rg;
#pragma unroll
        for (int reg = 0; reg < 4; ++reg)
          ((float*)Cv)[(row + reg) * (long)ldc + col] = acc[m][n][reg] + bv;
      }
    }
    return;
  }

  // ---- EP 0/1: LDS bounce for coalesced bf16x8 stores ----
#pragma unroll
  for (int n = 0; n < 4; ++n) {
    const int col = wc * 64 + n * 16 + lr;
    float bv = 0.f;
    if (EP == 1) {
      const long gcol = n0 + col;
      bv = (gcol < nbias) ? bias[gcol] : 0.f;
    }
#pragma unroll
    for (int m = 0; m < 8; ++m) {
      const int row = m * 32 + wr * 16 + lg * 4;
#pragma unroll
      for (int reg = 0; reg < 4; ++reg) {
        float v = acc[m][n][reg];
        if (EP == 1) { v += bv; v = v > 0.f ? v : 0.f; }
        smem[(row + reg) * 256 + col] = f2bf(v);
      }
    }
  }
  __builtin_amdgcn_s_barrier();
  const int rt = tid >> 5;          // 16 rows per pass
  const int ct = (tid & 31) * 8;    // 32 lanes x 8 cols = 256
  const long colg = n0 + ct;
  if (colg < Nvalid) {
#pragma unroll
    for (int p = 0; p < 16; ++p) {
      const int row = p * 16 + rt;
      bf16x8 v = *reinterpret_cast<const bf16x8*>(&smem[row * 256 + ct]);
      *reinterpret_cast<bf16x8*>(&((short*)Cv)[(m0 + row) * (long)ldc + colg]) = v;
    }
  }
}

// ---------------- gates: vectorized, 8 h per thread, bf16 hidden in ----------------
__global__ __launch_bounds__(256)
void gates_kernel(const float* __restrict__ prev_y,
                  const short* __restrict__ Ah,    // [B,H] bf16 (cast of prev_hidden)
                  const float* __restrict__ ccoarse,
                  const float* __restrict__ Icw,
                  const float* __restrict__ Ifw,
                  const float* __restrict__ bu,
                  const float* __restrict__ br,
                  const float* __restrict__ be,
                  const short* __restrict__ Rh,    // [B,2688] bf16
                  float* __restrict__ hid_out,
                  short* __restrict__ hid_bf)
{
  const int v = blockIdx.x * 256 + threadIdx.x;    // 0 .. B*112-1
  const int b = v / 112;
  const int h0 = (v - b * 112) * 8;
  const long rbase = (long)b * (3 * HH);

  const bf16x8 ru8 = *reinterpret_cast<const bf16x8*>(Rh + rbase + h0);
  const bf16x8 rr8 = *reinterpret_cast<const bf16x8*>(Rh + rbase + HH + h0);
  const bf16x8 re8 = *reinterpret_cast<const bf16x8*>(Rh + rbase + 2 * HH + h0);
  const bf16x8 ah8 = *reinterpret_cast<const bf16x8*>(Ah + (long)b * HH + h0);
  const float py0 = prev_y[2 * b], py1 = prev_y[2 * b + 1], c0 = ccoarse[b];

  float iu[8], ir[8], ie[8];
  if (h0 < SS) {
    const float4* cu = reinterpret_cast<const float4*>(Icw + 2 * h0);
    const float4* cr = reinterpret_cast<const float4*>(Icw + 2 * (SS + h0));
    const float4* ce = reinterpret_cast<const float4*>(Icw + 2 * (2 * SS + h0));
#pragma unroll
    for (int q = 0; q < 4; ++q) {
      float4 a = cu[q]; iu[2*q] = py0*a.x + py1*a.y; iu[2*q+1] = py0*a.z + py1*a.w;
      float4 r = cr[q]; ir[2*q] = py0*r.x + py1*r.y; ir[2*q+1] = py0*r.z + py1*r.w;
      float4 e = ce[q]; ie[2*q] = py0*e.x + py1*e.y; ie[2*q+1] = py0*e.z + py1*e.w;
    }
  } else {
    const int j0 = h0 - SS;
    const float* fu = Ifw + 3 * j0;
    const float* fr = Ifw + 3 * (SS + j0);
    const float* fe = Ifw + 3 * (2 * SS + j0);
#pragma unroll
    for (int j = 0; j < 8; ++j) {
      iu[j] = py0 * fu[3*j] + py1 * fu[3*j+1] + c0 * fu[3*j+2];
      ir[j] = py0 * fr[3*j] + py1 * fr[3*j+1] + c0 * fr[3*j+2];
      ie[j] = py0 * fe[3*j] + py1 * fe[3*j+1] + c0 * fe[3*j+2];
    }
  }
  const float4* bu4 = reinterpret_cast<const float4*>(bu + h0);
  const float4* br4 = reinterpret_cast<const float4*>(br + h0);
  const float4* be4 = reinterpret_cast<const float4*>(be + h0);
  float buv[8], brv[8], bev[8];
  { float4 a = bu4[0], b2 = bu4[1];
    buv[0]=a.x; buv[1]=a.y; buv[2]=a.z; buv[3]=a.w; buv[4]=b2.x; buv[5]=b2.y; buv[6]=b2.z; buv[7]=b2.w; }
  { float4 a = br4[0], b2 = br4[1];
    brv[0]=a.x; brv[1]=a.y; brv[2]=a.z; brv[3]=a.w; brv[4]=b2.x; brv[5]=b2.y; brv[6]=b2.z; brv[7]=b2.w; }
  { float4 a = be4[0], b2 = be4[1];
    bev[0]=a.x; bev[1]=a.y; bev[2]=a.z; bev[3]=a.w; bev[4]=b2.x; bev[5]=b2.y; bev[6]=b2.z; bev[7]=b2.w; }

  float hd[8];
  bf16x8 hb;
#pragma unroll
  for (int j = 0; j < 8; ++j) {
    float u = 1.f / (1.f + __expf(-(bf2f(ru8[j]) + iu[j] + buv[j])));
    float r = 1.f / (1.f + __expf(-(bf2f(rr8[j]) + ir[j] + brv[j])));
    float e = tanhf(r * bf2f(re8[j]) + ie[j] + bev[j]);
    hd[j] = u * bf2f(ah8[j]) + (1.f - u) * e;
    hb[j] = f2bf(hd[j]);
  }
  float4* ho = reinterpret_cast<float4*>(hid_out + (long)b * HH + h0);
  ho[0] = make_float4(hd[0], hd[1], hd[2], hd[3]);
  ho[1] = make_float4(hd[4], hd[5], hd[6], hd[7]);
  *reinterpret_cast<bf16x8*>(hid_bf + (long)b * HH + h0) = hb;
}

// ---------------- launch ----------------
extern "C" void kernel_launch(void* const* d_in, const int* in_sizes, int n_in,
                              void* d_out, int out_size, void* d_ws, size_t ws_size,
                              hipStream_t stream)
{
  (void)in_sizes; (void)n_in; (void)out_size; (void)ws_size;
  const float* prev_y      = (const float*)d_in[0];
  const float* prev_hidden = (const float*)d_in[1];
  const float* ccoarse     = (const float*)d_in[2];
  const float* R_w  = (const float*)d_in[3];
  const float* Ic_w = (const float*)d_in[4];
  const float* If_w = (const float*)d_in[5];
  const float* bu   = (const float*)d_in[6];
  const float* br   = (const float*)d_in[7];
  const float* be   = (const float*)d_in[8];
  const float* O1w  = (const float*)d_in[9];
  const float* O1b  = (const float*)d_in[10];
  const float* O2w  = (const float*)d_in[11];
  const float* O2b  = (const float*)d_in[12];
  const float* O3w  = (const float*)d_in[13];
  const float* O3b  = (const float*)d_in[14];
  const float* O4w  = (const float*)d_in[15];
  const float* O4b  = (const float*)d_in[16];

  float* out_coarse = (float*)d_out;
  float* out_fine   = out_coarse + (long)BB * QQ;
  float* hidden     = out_fine + (long)BB * QQ;

  char* ws = (char*)d_ws;
  short* Ah   = (short*)(ws + 0);          // B*H bf16           = 29,360,128 B
  short* Rwh  = (short*)(ws + 29360128);   // NPAD*H bf16        =  5,046,272 B
  short* Rh   = (short*)(ws + 34406400);   // B*2688 bf16        = 88,080,384 B
  short* hidb = (short*)(ws + 122486784);  // B*H bf16           = 29,360,128 B
  short* O1wb = (short*)(ws + 151846912);  // 512*448 bf16
  short* O3wb = (short*)(ws + 152305664);
  short* O2wb = (short*)(ws + 152764416);  // 256*512 bf16
  short* O4wb = (short*)(ws + 153026560);  // end: 153,288,704 B
  // t1/t2 alias the Ah+Rwh region (dead after the R-GEMM)
  short* t1   = (short*)(ws + 0);          // B*512 bf16 = 16,777,216 B
  short* t2   = (short*)(ws + 16777216);   // ends 33,554,432 < 34,406,400 OK

  // all casts in one launch (4,481,024 four-elem units)
  castall_kernel<<<17504, 256, 0, stream>>>(prev_hidden, Ah, R_w, Rwh,
                                            O1w, O1wb, O3w, O3wb, O2w, O2wb, O4w, O4wb);

  // R GEMM: M=B, N=2816 (valid 2688), K=896 -> Rh bf16 (ldc 2688, col-guarded)
  gemm256_bt<0><<<dim3(704, 1, 1), 512, 0, stream>>>(
      Ah, Ah, HH, Rwh, Rwh, HH, Rh, Rh, 3 * HH,
      nullptr, nullptr, 0, 3 * HH, HH, NPAD / 256);

  // gates -> hidden (f32 to d_out) + hidb (bf16)
  gates_kernel<<<BB * 112 / 256, 256, 0, stream>>>(prev_y, Ah, ccoarse,
                                                   Ic_w, If_w, bu, br, be, Rh, hidden, hidb);

  // heads layer 1: t = relu(h_half @ O^T + b), N=512 (448 valid bias), K=448
  gemm256_bt<1><<<dim3(128, 1, 2), 512, 0, stream>>>(
      hidb, hidb + 448, HH, O1wb, O3wb, 448, t1, t2, 512,
      O1b, O3b, 448, 512, 448, 2);

  // heads layer 2: out = t @ O^T + b (f32), N=256, K=512
  gemm256_bt<2><<<dim3(64, 1, 2), 512, 0, stream>>>(
      t1, t2, 512, O2wb, O4wb, 512, out_coarse, out_fine, QQ,
      O2b, O4b, QQ, QQ, 512, 1);
}